// Round 10
// baseline (356.222 us; speedup 1.0000x reference)
//
#include <hip/hip_runtime.h>
#include <hip/hip_fp16.h>
#include <math.h>

typedef _Float16 f16;
typedef _Float16 f16x2 __attribute__((ext_vector_type(2)));
typedef _Float16 f16x8 __attribute__((ext_vector_type(8)));
typedef float f32x4 __attribute__((ext_vector_type(4)));
typedef unsigned char u8;

#define HDIM 256
#define TST 128
#define OUTD 10
#define S2LE 2.8853900817779268f   // 2*log2(e)

static __device__ __forceinline__ f16x2 pkrtz(float a, float b) {
  auto r = __builtin_amdgcn_cvt_pkrtz(a, b);
  return *(f16x2*)&r;
}

// 8 waves/block (512 thr), wave owns 32 hidden rows (wf[2][8]=64 VGPR);
// block owns 32 batch cols in 2 groups; double-pump (R8/R9). 512 blocks =
// 2 blocks/CU, 16 waves/CU = 4 waves/SIMD (launch_bounds(512,4) => <=128 reg).
// Stats: each wave MFMA-Grams ONLY its own chunk (2 MFMAs, no 8x redundancy);
// partials exchanged in padded LDS, summed post-barrier by consumers.
__global__ __launch_bounds__(512, 4) void rnn_kernel(
    const float* __restrict__ x,
    const float* __restrict__ embed_w,
    const float* __restrict__ embed_b,
    const float* __restrict__ update_w,
    const float* __restrict__ update_b,
    const float* __restrict__ gamma,
    const float* __restrict__ beta,
    const float* __restrict__ out_w,
    const float* __restrict__ out_b,
    float* __restrict__ out)
{
  __shared__ __align__(16) f16   sFR[2][8][64][8];   // 16 KB; overlays: T0 (init), sOut (epi)
  __shared__ __align__(16) float sD1[10 * 260];      // 10.4 KB; epi overlay: sOW
  __shared__ __align__(16) float sBW[HDIM];
  __shared__ __align__(16) float sRSg[HDIM];
  __shared__ __align__(16) float sST[2][16][10][2];  // [g][col][wave(8 used, pad 10)][s1,s2]
  __shared__ float sOB[16];
  __shared__ u8    sXb[TST][32];

  const int tid = threadIdx.x;
  const int w  = tid >> 6;      // 0..7
  const int l  = tid & 63;
  const int q  = l >> 4;
  const int ml = l & 15;
  const int m3 = ml & 3;
  const int base = blockIdx.x * 32;
  const int nb = w * 32 + q * 4;          // rows [32w,32w+32): nt in {0,1}
  const int diagw = (q == (ml >> 2));     // lane holds Gram diag for col ml

  float* T0 = (float*)&sFR[0][0][0][0];   // [256][10] init-only overlay

  // ---------- P-init 1 ----------
  if (tid < 256) {
    float ew = embed_w[tid], eb = embed_b[tid];
    #pragma unroll
    for (int xv = 0; xv < 10; xv++)
      T0[tid * 10 + xv] = tanhf((float)xv * ew + eb);
  }
  for (int idx = tid; idx < 32 * TST; idx += 512) {
    int col = idx >> 7, tt = idx & 127;
    sXb[tt][col] = (u8)(int)x[(size_t)(base + col) * TST + tt];
  }
  if (tid < 16) {
    float v = 0.f;
    if (tid < OUTD) {
      v = out_b[tid];
      const float* orow = out_w + tid * HDIM;
      for (int k = 0; k < HDIM; k += 4) {
        float4 wv = *(const float4*)(orow + k);
        float4 bv = *(const float4*)(beta + k);
        v = fmaf(wv.x, bv.x, fmaf(wv.y, bv.y, fmaf(wv.z, bv.z, fmaf(wv.w, bv.w, v))));
      }
    }
    sOB[tid] = v;
  }
  __syncthreads();

  // ---------- P-init 2: per-n tables (n = tid < 256) ----------
  if (tid < 256) {
    const int n = tid;
    const float* wrow = update_w + n * HDIM;
    float ty[10];
    #pragma unroll
    for (int xv = 0; xv < 10; xv++) ty[xv] = 0.f;
    float bw = 0.f, rsg = 0.f;
    for (int k = 0; k < HDIM; k += 4) {
      float4 wv4 = *(const float4*)(wrow + k);
      float4 b4  = *(const float4*)(beta + k);
      float4 g4  = *(const float4*)(gamma + k);
      bw  = fmaf(wv4.x, b4.x, fmaf(wv4.y, b4.y, fmaf(wv4.z, b4.z, fmaf(wv4.w, b4.w, bw))));
      rsg = fmaf(wv4.x, S2LE * g4.x, fmaf(wv4.y, S2LE * g4.y,
            fmaf(wv4.z, S2LE * g4.z, fmaf(wv4.w, S2LE * g4.w, rsg))));
      #pragma unroll
      for (int kk = 0; kk < 4; kk++) {
        float wv = ((const float*)&wv4)[kk];
        const float* t0r = T0 + (k + kk) * 10;
        #pragma unroll
        for (int xv = 0; xv < 10; xv++) ty[xv] = fmaf(wv, t0r[xv], ty[xv]);
      }
    }
    float ubn = update_b[n];
    sBW[n]  = S2LE * bw;
    sRSg[n] = rsg;
    #pragma unroll
    for (int xv = 0; xv < 10; xv++)
      sD1[xv * 260 + n] = S2LE * (ty[xv] + ubn + bw);
  }
  __syncthreads();

  // ---------- W_g fragments: 64 VGPR ----------
  f16x8 wf[2][8];
  #pragma unroll
  for (int c = 0; c < 8; c++) {
    const int k0 = c * 32 + q * 4;
    float4 g0 = *(const float4*)(gamma + k0);
    float4 g1 = *(const float4*)(gamma + k0 + 16);
    #pragma unroll
    for (int nt = 0; nt < 2; nt++) {
      const float* wrow = update_w + (w * 32 + nt * 16 + ml) * HDIM;
      float4 a0 = *(const float4*)(wrow + k0);
      float4 a1 = *(const float4*)(wrow + k0 + 16);
      f16x8 f;
      f[0]=(f16)(S2LE*g0.x*a0.x); f[1]=(f16)(S2LE*g0.y*a0.y);
      f[2]=(f16)(S2LE*g0.z*a0.z); f[3]=(f16)(S2LE*g0.w*a0.w);
      f[4]=(f16)(S2LE*g1.x*a1.x); f[5]=(f16)(S2LE*g1.y*a1.y);
      f[6]=(f16)(S2LE*g1.z*a1.z); f[7]=(f16)(S2LE*g1.w*a1.w);
      wf[nt][c] = f;
    }
  }
  f32x4 rsgr[2];
  rsgr[0] = *(const f32x4*)(sRSg + nb);
  rsgr[1] = *(const f32x4*)(sRSg + nb + 16);

  f32x4 acc0[2], acc1[2];

  // ---------- prologue t=0: tv(0) both groups; wave packs OWN chunk ----------
  {
    #pragma unroll
    for (int g = 0; g < 2; g++) {
      const int xv0 = (int)sXb[0][g * 16 + ml];
      const float* dp = sD1 + xv0 * 260;
      f32x4 bw0 = *(const f32x4*)(sBW + nb);
      f32x4 bw1 = *(const f32x4*)(sBW + nb + 16);
      f32x4 dd0 = *(const f32x4*)(dp + nb);
      f32x4 dd1 = *(const f32x4*)(dp + nb + 16);
      float t0v[4], t1v[4];
      #pragma unroll
      for (int r = 0; r < 4; r++) {
        float y0 = dd0[r] - bw0[r];
        float e0 = __builtin_amdgcn_exp2f(y0);
        t0v[r] = fmaf(-2.f, __builtin_amdgcn_rcpf(e0 + 1.f), 1.f);
        float y1 = dd1[r] - bw1[r];
        float e1 = __builtin_amdgcn_exp2f(y1);
        t1v[r] = fmaf(-2.f, __builtin_amdgcn_rcpf(e1 + 1.f), 1.f);
      }
      union { f16x8 v8; f16x2 v2[4]; } pk;
      pk.v2[0] = pkrtz(t0v[0], t0v[1]);
      pk.v2[1] = pkrtz(t0v[2], t0v[3]);
      pk.v2[2] = pkrtz(t1v[0], t1v[1]);
      pk.v2[3] = pkrtz(t1v[2], t1v[3]);
      *(f16x8*)&sFR[g][w][l][0] = pk.v8;
    }
    __syncthreads();
  }

#define MMG2(FB, CC, CUR, NXT, ACC)                                            \
    { if ((CC) < 7) NXT = *(const f16x8*)((FB) + ((CC) + 1) * 512 + l * 8);    \
      ACC[0] = __builtin_amdgcn_mfma_f32_16x16x32_f16(wf[0][CC], CUR, ACC[0],0,0,0); \
      ACC[1] = __builtin_amdgcn_mfma_f32_16x16x32_f16(wf[1][CC], CUR, ACC[1],0,0,0); }

#define STATMM(RO, AG, AS)                                                     \
    { f16x8 ones_;                                                             \
      _Pragma("unroll") for (int j_ = 0; j_ < 8; j_++) ones_[j_] = (f16)1.f;   \
      AG = __builtin_amdgcn_mfma_f32_16x16x32_f16(RO, RO, AG, 0, 0, 0);        \
      AS = __builtin_amdgcn_mfma_f32_16x16x32_f16(ones_, RO, AS, 0, 0, 0); }

#define STATWR(G, AG, AS)                                                      \
    { float sel_ = AG[0];                                                      \
      sel_ = (m3 == 1) ? AG[1] : sel_;                                         \
      sel_ = (m3 == 2) ? AG[2] : sel_;                                         \
      sel_ = (m3 == 3) ? AG[3] : sel_;                                         \
      if (diagw) *(float2*)&sST[G][ml][w][0] = make_float2(AS[0], sel_); }

#define STATRD(G, S1, S2)                                                      \
    { const float* sp_ = &sST[G][ml][0][0];                                    \
      f32x4 a0_ = *(const f32x4*)(sp_);                                        \
      f32x4 a1_ = *(const f32x4*)(sp_ + 4);                                    \
      f32x4 a2_ = *(const f32x4*)(sp_ + 8);                                    \
      f32x4 a3_ = *(const f32x4*)(sp_ + 12);                                   \
      S1 = ((a0_[0] + a0_[2]) + (a1_[0] + a1_[2]))                             \
         + ((a2_[0] + a2_[2]) + (a3_[0] + a3_[2]));                            \
      S2 = ((a0_[1] + a0_[3]) + (a1_[1] + a1_[3]))                             \
         + ((a2_[1] + a2_[3]) + (a3_[1] + a3_[3])); }

#define SLICEH(H, ACCE, DD, TVV)                                               \
    { _Pragma("unroll") for (int r_ = 0; r_ < 4; r_++) {                       \
        float y_ = fmaf(rs_, ACCE[H][r_], fmaf(-rm_, rsgr[H][r_], DD[r_]));    \
        float e_ = __builtin_amdgcn_exp2f(y_);                                 \
        TVV[r_] = fmaf(-2.f, __builtin_amdgcn_rcpf(e_ + 1.f), 1.f); } }

// PHASE: MFMA group GM (frags -> ACCM; own-chunk Gram -> sST[GM]) ||
// elementwise group GE at step TE (consumes ACCE + sST[GE]; packs own chunk).
#define PHASE(TE, GM, GE, XOFF, ACCM, ACCE)                                    \
  {                                                                            \
    float s1_, s2_;                                                            \
    STATRD(GE, s1_, s2_)                                                       \
    const int xv_ = (int)sXb[TE][XOFF + ml];                                   \
    const float* dp_ = sD1 + xv_ * 260 + nb;                                   \
    f32x4 dd0_ = *(const f32x4*)(dp_);                                         \
    f32x4 dd1_ = *(const f32x4*)(dp_ + 16);                                    \
    const f16* fbm_ = &sFR[GM][0][0][0];                                       \
    f16x8 rOwn_ = *(const f16x8*)(fbm_ + w * 512 + l * 8);                     \
    f32x4 aG_ = {0.f,0.f,0.f,0.f}, aS_ = {0.f,0.f,0.f,0.f};                    \
    STATMM(rOwn_, aG_, aS_)                                                    \
    f16x8 rA_ = *(const f16x8*)(fbm_ + l * 8);                                 \
    f16x8 rB_;                                                                 \
    ACCM[0] = (f32x4){0.f, 0.f, 0.f, 0.f};                                     \
    ACCM[1] = (f32x4){0.f, 0.f, 0.f, 0.f};                                     \
    __builtin_amdgcn_s_setprio(1);                                             \
    MMG2(fbm_, 0, rA_, rB_, ACCM)                                              \
    MMG2(fbm_, 1, rB_, rA_, ACCM)                                              \
    float mu_ = s1_ * (1.f / 256.f);                                           \
    float rs_ = __frsqrt_rn(fmaf(s2_, 1.f / 256.f, -mu_ * mu_) + 1e-5f);       \
    float rm_ = rs_ * mu_;                                                     \
    float t0_[4], t1_[4];                                                      \
    MMG2(fbm_, 2, rA_, rB_, ACCM)                                              \
    SLICEH(0, ACCE, dd0_, t0_)                                                 \
    MMG2(fbm_, 3, rB_, rA_, ACCM)                                              \
    MMG2(fbm_, 4, rA_, rB_, ACCM)                                              \
    SLICEH(1, ACCE, dd1_, t1_)                                                 \
    MMG2(fbm_, 5, rB_, rA_, ACCM)                                              \
    {                                                                          \
      union { f16x8 v8; f16x2 v2[4]; } k_;                                     \
      k_.v2[0] = pkrtz(t0_[0], t0_[1]);                                        \
      k_.v2[1] = pkrtz(t0_[2], t0_[3]);                                        \
      k_.v2[2] = pkrtz(t1_[0], t1_[1]);                                        \
      k_.v2[3] = pkrtz(t1_[2], t1_[3]);                                        \
      *(f16x8*)&sFR[GE][w][l][0] = k_.v8;                                      \
    }                                                                          \
    MMG2(fbm_, 6, rA_, rB_, ACCM)                                              \
    MMG2(fbm_, 7, rB_, rA_, ACCM)                                              \
    __builtin_amdgcn_s_setprio(0);                                             \
    STATWR(GM, aG_, aS_)                                                       \
    __syncthreads();                                                           \
  }

  // ---------- P0(1): MFMA g0 + own-chunk stats(g0,0) ----------
  {
    const f16* fbm_ = &sFR[0][0][0][0];
    f16x8 rOwn_ = *(const f16x8*)(fbm_ + w * 512 + l * 8);
    f32x4 aG_ = {0.f,0.f,0.f,0.f}, aS_ = {0.f,0.f,0.f,0.f};
    STATMM(rOwn_, aG_, aS_)
    f16x8 rA_ = *(const f16x8*)(fbm_ + l * 8);
    f16x8 rB_;
    acc0[0] = (f32x4){0.f, 0.f, 0.f, 0.f};
    acc0[1] = (f32x4){0.f, 0.f, 0.f, 0.f};
    MMG2(fbm_, 0, rA_, rB_, acc0)
    MMG2(fbm_, 1, rB_, rA_, acc0)
    MMG2(fbm_, 2, rA_, rB_, acc0)
    MMG2(fbm_, 3, rB_, rA_, acc0)
    MMG2(fbm_, 4, rA_, rB_, acc0)
    MMG2(fbm_, 5, rB_, rA_, acc0)
    MMG2(fbm_, 6, rA_, rB_, acc0)
    MMG2(fbm_, 7, rB_, rA_, acc0)
    STATWR(0, aG_, aS_)
    __syncthreads();
  }

  // ---------- main loop ----------
  #pragma unroll 1
  for (int t = 1; t <= 127; t++) {
    PHASE(t, 1, 0, 0,  acc1, acc0)
    PHASE(t, 0, 1, 16, acc0, acc1)
  }
  // post: sFR[0]=tv(g0,127), sFR[1]=tv(g1,127); sST[0]=partials(tv(g0,127));
  //       sST[1] stale (tv(g1,126)) -> mini-phase below.

  // ---------- epilogue ----------
  {
    // stats(g1,127): own-chunk Gram on sFR[1]
    f16x8 fin1 = *(const f16x8*)&sFR[1][w][l][0];
    f32x4 aG2 = {0.f,0.f,0.f,0.f}, aS2 = {0.f,0.f,0.f,0.f};
    STATMM(fin1, aG2, aS2)
    STATWR(1, aG2, aS2)
    f16x8 fin0 = *(const f16x8*)&sFR[0][w][l][0];
    __syncthreads();

    float rsF[2], nmF[2];
    {
      float s1, s2;
      STATRD(0, s1, s2)
      float mu = s1 * (1.f / 256.f);
      float ve = fmaf(s2, 1.f / 256.f, -mu * mu) + 1e-5f;
      rsF[0] = __frsqrt_rn(ve); nmF[0] = -rsF[0] * mu;
      STATRD(1, s1, s2)
      mu = s1 * (1.f / 256.f);
      ve = fmaf(s2, 1.f / 256.f, -mu * mu) + 1e-5f;
      rsF[1] = __frsqrt_rn(ve); nmF[1] = -rsF[1] * mu;
    }

    // build sOW (gamma-folded out_w frags) over sD1
    f16* sOW = (f16*)sD1;
    {
      int c = tid >> 6, l2 = tid & 63, q2 = l2 >> 4, o = l2 & 15;
      int k0 = c * 32 + q2 * 4;
      f16x8 f;
      #pragma unroll
      for (int j = 0; j < 8; j++) f[j] = (f16)0.f;
      if (o < OUTD) {
        const float* orow = out_w + o * HDIM;
        float4 a0 = *(const float4*)(orow + k0);
        float4 a1 = *(const float4*)(orow + k0 + 16);
        float4 g0 = *(const float4*)(gamma + k0);
        float4 g1 = *(const float4*)(gamma + k0 + 16);
        f[0]=(f16)(g0.x*a0.x); f[1]=(f16)(g0.y*a0.y); f[2]=(f16)(g0.z*a0.z); f[3]=(f16)(g0.w*a0.w);
        f[4]=(f16)(g1.x*a1.x); f[5]=(f16)(g1.y*a1.y); f[6]=(f16)(g1.z*a1.z); f[7]=(f16)(g1.w*a1.w);
      }
      *(f16x8*)(sOW + (size_t)tid * 8) = f;
    }
    __syncthreads();   // fin0/fin1 read above; sOut overlay writes below

    float* sOut = (float*)&sFR[0][0][0][0];  // [2][8][16][16] f32 = 16 KB overlay
    f16x8 of = *(const f16x8*)(sOW + ((size_t)w * 64 + l) * 8);
    #pragma unroll
    for (int g = 0; g < 2; g++) {
      f16x8 fin = (g == 0) ? fin0 : fin1;
      f16x8 af;
      #pragma unroll
      for (int j = 0; j < 8; j++)
        af[j] = (f16)fmaf(rsF[g], (float)fin[j], nmF[g]);
      f32x4 aO = {0.f, 0.f, 0.f, 0.f};
      aO = __builtin_amdgcn_mfma_f32_16x16x32_f16(of, af, aO, 0, 0, 0);
      #pragma unroll
      for (int r = 0; r < 4; r++)
        sOut[(((g * 8 + w) * 16) + ml) * 16 + q * 4 + r] = aO[r];
    }
    __syncthreads();
    if (tid < 32 * OUTD) {
      int m = tid / OUTD, o = tid - m * OUTD;
      int g = m >> 4, mm = m & 15;
      float s = 0.f;
      #pragma unroll
      for (int ww = 0; ww < 8; ww++)
        s += sOut[(((g * 8 + ww) * 16) + mm) * 16 + o];
      out[(size_t)(base + m) * OUTD + o] = s + sOB[o];
    }
  }
}

extern "C" void kernel_launch(void* const* d_in, const int* in_sizes, int n_in,
                              void* d_out, int out_size, void* d_ws, size_t ws_size,
                              hipStream_t stream) {
  const float* x   = (const float*)d_in[0];
  const float* ew  = (const float*)d_in[1];
  const float* eb  = (const float*)d_in[2];
  const float* uw  = (const float*)d_in[3];
  const float* ub  = (const float*)d_in[4];
  const float* g   = (const float*)d_in[5];
  const float* be  = (const float*)d_in[6];
  const float* ow  = (const float*)d_in[7];
  const float* ob  = (const float*)d_in[8];
  float* out = (float*)d_out;

  const int B = in_sizes[0] / TST;      // 16384
  const int grid = B / 32;              // 512 blocks x 512 thr = 2 blocks/CU
  hipLaunchKernelGGL(rnn_kernel, dim3(grid), dim3(512), 0, stream,
                     x, ew, eb, uw, ub, g, be, ow, ob, out);
}